// Round 1
// baseline (1023.773 us; speedup 1.0000x reference)
//
#include <hip/hip_runtime.h>

#pragma clang fp contract(off)

typedef unsigned long long u64;
typedef unsigned int u32;

#define NB 8192
#define NW 128          // NB/64 suppression words

// workspace layout (bytes)
#define OFF_MAT   0
#define SZ_MAT    (NB * NW * 8)            // 8 MB IoU bit-matrix
#define OFF_KEYS  (SZ_MAT)                 // u64[NB]
#define OFF_ORDER (OFF_KEYS  + NB * 8)     // int[NB]
#define OFF_EDGE  (OFF_ORDER + NB * 4)     // float[NB]
#define OFF_MP    (OFF_EDGE  + NB * 4)     // float[NB]
#define OFF_Q     (OFF_MP    + NB * 4)     // float[NB]
#define OFF_X1    (OFF_Q     + NB * 4)
#define OFF_Y1    (OFF_X1    + NB * 4)
#define OFF_X2    (OFF_Y1    + NB * 4)
#define OFF_Y2    (OFF_X2    + NB * 4)
#define OFF_AR    (OFF_Y2    + NB * 4)
#define OFF_KEEP  (OFF_AR    + NB * 4)     // u64[NW]

__device__ __forceinline__ float haar3(float a, float b, float c, float d) {
    return fabsf(a + b - c - d) + fabsf(a - b + c - d) + fabsf(a - b - c + d);
}

// ---------- K1: per-box edge quality from 64x64 features ----------
__global__ __launch_bounds__(256) void k_edge(const float* __restrict__ feat,
                                              float* __restrict__ edgeq) {
    int n = blockIdx.x;
    const float* f = feat + (size_t)n * 4096;
    int t = threadIdx.x;
    int hr = t >> 3, g = t & 7;                 // haar row 0..31, group 0..7
    const float4* row0 = (const float4*)(f + (2 * hr) * 64);
    const float4* row1 = (const float4*)(f + (2 * hr) * 64 + 64);
    float4 e0 = row0[g];
    float4 e1 = row0[8 + g];
    float4 o0 = row1[g];
    float4 o1 = row1[8 + g];
    float s = haar3(e0.x, e0.y, o0.x, o0.y) + haar3(e0.z, e0.w, o0.z, o0.w)
            + haar3(e1.x, e1.y, o1.x, o1.y) + haar3(e1.z, e1.w, o1.z, o1.w);
    for (int off = 32; off; off >>= 1) s += __shfl_down(s, off, 64);
    __shared__ float wsum[4];
    int wv = t >> 6, ln = t & 63;
    if (ln == 0) wsum[wv] = s;
    __syncthreads();
    if (t == 0) edgeq[n] = (wsum[0] + wsum[1] + wsum[2] + wsum[3]) * (0.5f / 3072.0f);
}

// ---------- K2: per-row max softmax prob over 1000 logits ----------
__global__ __launch_bounds__(256) void k_logit(const float* __restrict__ logits,
                                               float* __restrict__ mp) {
    int wave = threadIdx.x >> 6, lane = threadIdx.x & 63;
    int row = blockIdx.x * 4 + wave;
    const float4* p = (const float4*)(logits + (size_t)row * 1000);
    float4 v0 = p[lane];
    float4 v1 = p[lane + 64];
    float4 v2 = p[lane + 128];
    bool has3 = (lane + 192) < 250;
    float4 v3 = p[has3 ? (lane + 192) : lane];
    float m = fmaxf(fmaxf(fmaxf(v0.x, v0.y), fmaxf(v0.z, v0.w)),
                    fmaxf(fmaxf(v1.x, v1.y), fmaxf(v1.z, v1.w)));
    m = fmaxf(m, fmaxf(fmaxf(v2.x, v2.y), fmaxf(v2.z, v2.w)));
    if (has3) m = fmaxf(m, fmaxf(fmaxf(v3.x, v3.y), fmaxf(v3.z, v3.w)));
    for (int off = 32; off; off >>= 1) m = fmaxf(m, __shfl_xor(m, off, 64));
    float s = expf(v0.x - m) + expf(v0.y - m) + expf(v0.z - m) + expf(v0.w - m)
            + expf(v1.x - m) + expf(v1.y - m) + expf(v1.z - m) + expf(v1.w - m)
            + expf(v2.x - m) + expf(v2.y - m) + expf(v2.z - m) + expf(v2.w - m);
    if (has3) s += expf(v3.x - m) + expf(v3.y - m) + expf(v3.z - m) + expf(v3.w - m);
    for (int off = 32; off; off >>= 1) s += __shfl_xor(s, off, 64);
    if (lane == 0) mp[row] = 1.0f / s;
}

// ---------- K3: quality + sort keys (single block) ----------
__global__ __launch_bounds__(1024) void k_quality(const float* __restrict__ boxes,
        const float* __restrict__ scores, const float* __restrict__ edgeq,
        const float* __restrict__ mp, float* __restrict__ quality,
        u64* __restrict__ keys) {
    int tid = threadIdx.x;
    float amax = 0.f;
    float areaLoc[8];
    #pragma unroll
    for (int t = 0; t < 8; ++t) {
        int i = tid + t * 1024;
        float4 b = ((const float4*)boxes)[i];
        float w = b.z - b.x, h = b.w - b.y;
        areaLoc[t] = w * h;
        amax = fmaxf(amax, areaLoc[t]);
    }
    for (int off = 32; off; off >>= 1) amax = fmaxf(amax, __shfl_xor(amax, off, 64));
    __shared__ float wmax[16];
    int wv = tid >> 6, ln = tid & 63;
    if (ln == 0) wmax[wv] = amax;
    __syncthreads();
    if (tid == 0) {
        float mm = wmax[0];
        for (int k = 1; k < 16; ++k) mm = fmaxf(mm, wmax[k]);
        wmax[0] = mm;
    }
    __syncthreads();
    float maxA = wmax[0];
    #pragma unroll
    for (int t = 0; t < 8; ++t) {
        int i = tid + t * 1024;
        float4 b = ((const float4*)boxes)[i];
        float w = b.z - b.x, h = b.w - b.y;
        float aspect = fminf(w / h, h / w);
        float ascore = areaLoc[t] / (maxA + 1e-6f);
        ascore = fminf(fmaxf(ascore, 0.f), 1.f);
        float det = scores[i] * mp[i] * (aspect * ascore);
        float q = det * 0.4f + 0.3f + edgeq[i] * 0.3f;
        quality[i] = q;
        u32 sb = __float_as_uint(scores[i]);
        sb ^= (sb >> 31) ? 0xFFFFFFFFu : 0x80000000u;   // order-preserving flip
        keys[i] = ((u64)sb << 32) | (u64)(0xFFFFFFFFu - (u32)i);
    }
}

// ---------- K4: bitonic descending sort of 8192 u64 keys (single block) ----------
__global__ __launch_bounds__(1024) void k_sort(const u64* __restrict__ keysIn,
        const float* __restrict__ boxes, int* __restrict__ order,
        float* __restrict__ x1s, float* __restrict__ y1s,
        float* __restrict__ x2s, float* __restrict__ y2s,
        float* __restrict__ ars) {
    __shared__ u64 k[NB];
    int tid = threadIdx.x;
    #pragma unroll
    for (int t = 0; t < 8; ++t) k[tid + t * 1024] = keysIn[tid + t * 1024];
    __syncthreads();
    for (int size = 2; size <= NB; size <<= 1) {
        for (int stride = size >> 1; stride > 0; stride >>= 1) {
            #pragma unroll
            for (int t = 0; t < 4; ++t) {
                int p = tid + t * 1024;
                int i = ((p & ~(stride - 1)) << 1) | (p & (stride - 1));
                int l = i + stride;
                bool down = ((i & size) == 0);
                u64 a = k[i], b = k[l];
                bool sw = down ? (a < b) : (a > b);
                if (sw) { k[i] = b; k[l] = a; }
            }
            __syncthreads();
        }
    }
    #pragma unroll
    for (int t = 0; t < 8; ++t) {
        int i = tid + t * 1024;
        int n = (int)(0xFFFFFFFFu - (u32)(k[i] & 0xFFFFFFFFull));
        order[i] = n;
        float4 b = ((const float4*)boxes)[n];
        x1s[i] = b.x; y1s[i] = b.y; x2s[i] = b.z; y2s[i] = b.w;
        ars[i] = (b.z - b.x) * (b.w - b.y);
    }
}

// ---------- K5: IoU suppression bit-matrix, upper triangle ----------
__global__ __launch_bounds__(64) void k_mat(const float* __restrict__ x1s,
        const float* __restrict__ y1s, const float* __restrict__ x2s,
        const float* __restrict__ y2s, const float* __restrict__ ars,
        u64* __restrict__ mat) {
    int jt = blockIdx.x, it = blockIdx.y;
    if (jt < it) return;
    int lane = threadIdx.x;
    __shared__ float cx1[64], cy1[64], cx2[64], cy2[64], car[64];
    int j0 = jt * 64;
    cx1[lane] = x1s[j0 + lane]; cy1[lane] = y1s[j0 + lane];
    cx2[lane] = x2s[j0 + lane]; cy2[lane] = y2s[j0 + lane];
    car[lane] = ars[j0 + lane];
    __syncthreads();
    int i = it * 64 + lane;
    float X1 = x1s[i], Y1 = y1s[i], X2 = x2s[i], Y2 = y2s[i], AR = ars[i];
    u64 word = 0;
    #pragma unroll 4
    for (int b = 0; b < 64; ++b) {
        int j = j0 + b;
        float xx1 = fmaxf(cx1[b], X1);
        float yy1 = fmaxf(cy1[b], Y1);
        float xx2 = fminf(cx2[b], X2);
        float yy2 = fminf(cy2[b], Y2);
        float iw = fmaxf(xx2 - xx1, 0.0f);
        float ih = fmaxf(yy2 - yy1, 0.0f);
        float inter = iw * ih;
        float denom = (AR + car[b]) - inter;
        float iou = inter / denom;
        if ((iou > 0.5f) && (j > i)) word |= (1ull << b);
    }
    mat[(size_t)i * NW + jt] = word;
}

// ---------- K6: serial greedy scan, single wave, prefetched rows ----------
#define PREF(R0, R1, ROWBASE) do {                                             \
    _Pragma("unroll")                                                          \
    for (int r = 0; r < 8; ++r) {                                              \
        ulonglong2 v = *(const ulonglong2*)(mat + (size_t)((ROWBASE) + r) * NW \
                                            + 2 * lane);                       \
        R0[r] = v.x; R1[r] = v.y;                                              \
    }                                                                          \
} while (0)

#define PROC(R0, R1, IBASE) do {                                               \
    _Pragma("unroll")                                                          \
    for (int b = 0; b < 8; ++b) {                                              \
        int i = (IBASE) + b;                                                   \
        int wi = i >> 6;                                                       \
        if ((i & 63) == 0) {                                                   \
            u64 w = (wi & 1) ? sup1 : sup0;                                    \
            cur = __shfl(w, wi >> 1, 64);                                      \
        }                                                                      \
        bool kept = ((cur >> (i & 63)) & 1ull) == 0ull;                        \
        if (kept) {                                                            \
            if (lane == (wi >> 1)) {                                           \
                if (wi & 1) keep1 |= (1ull << (i & 63));                       \
                else        keep0 |= (1ull << (i & 63));                       \
            }                                                                  \
            u64 m0 = (2 * lane     >= wi) ? R0[b] : 0ull;                      \
            u64 m1 = (2 * lane + 1 >= wi) ? R1[b] : 0ull;                      \
            sup0 |= m0; sup1 |= m1;                                            \
            u64 dw = (wi & 1) ? R1[b] : R0[b];                                 \
            cur |= __shfl(dw, wi >> 1, 64);                                    \
        }                                                                      \
    }                                                                          \
} while (0)

__global__ __launch_bounds__(64) void k_scan(const u64* __restrict__ mat,
                                             u64* __restrict__ keepmask) {
    int lane = threadIdx.x;
    u64 sup0 = 0, sup1 = 0, keep0 = 0, keep1 = 0, cur = 0;
    u64 a0[8], a1[8], b0[8], b1[8];
    PREF(a0, a1, 0);
    for (int basei = 0; basei < NB; basei += 16) {
        PREF(b0, b1, basei + 8);
        PROC(a0, a1, basei);
        if (basei + 16 < NB) PREF(a0, a1, basei + 16);
        PROC(b0, b1, basei + 8);
    }
    keepmask[2 * lane]     = keep0;
    keepmask[2 * lane + 1] = keep1;
}

// ---------- K7: final outputs ----------
__global__ __launch_bounds__(256) void k_out(const float* __restrict__ boxes,
        const float* __restrict__ scores, const float* __restrict__ quality,
        const int* __restrict__ order, const u64* __restrict__ keepmask,
        const int* __restrict__ labels, float* __restrict__ out) {
    int i = blockIdx.x * 256 + threadIdx.x;    // sorted position
    int n = order[i];
    bool kept = (keepmask[i >> 6] >> (i & 63)) & 1ull;
    float kf = kept ? 1.0f : 0.0f;
    float4 b = ((const float4*)boxes)[n];
    float* o = out + (size_t)n * 6;
    o[0] = b.x * kf; o[1] = b.y * kf; o[2] = b.z * kf; o[3] = b.w * kf;
    o[4] = scores[n] * kf;
    o[5] = quality[n] * kf;
    out[6 * NB + n] = kf;
    out[7 * NB + n] = (float)labels[n];
}

extern "C" void kernel_launch(void* const* d_in, const int* in_sizes, int n_in,
                              void* d_out, int out_size, void* d_ws, size_t ws_size,
                              hipStream_t stream) {
    const float* boxes  = (const float*)d_in[0];
    const float* scores = (const float*)d_in[1];
    const float* logits = (const float*)d_in[2];
    const float* feats  = (const float*)d_in[3];
    const int*   labels = (const int*)d_in[4];
    float* out = (float*)d_out;
    char* ws = (char*)d_ws;

    u64*   mat    = (u64*)(ws + OFF_MAT);
    u64*   keys   = (u64*)(ws + OFF_KEYS);
    int*   order  = (int*)(ws + OFF_ORDER);
    float* edgeq  = (float*)(ws + OFF_EDGE);
    float* mp     = (float*)(ws + OFF_MP);
    float* qual   = (float*)(ws + OFF_Q);
    float* x1s    = (float*)(ws + OFF_X1);
    float* y1s    = (float*)(ws + OFF_Y1);
    float* x2s    = (float*)(ws + OFF_X2);
    float* y2s    = (float*)(ws + OFF_Y2);
    float* ars    = (float*)(ws + OFF_AR);
    u64*   keepm  = (u64*)(ws + OFF_KEEP);

    k_edge<<<NB, 256, 0, stream>>>(feats, edgeq);
    k_logit<<<NB / 4, 256, 0, stream>>>(logits, mp);
    k_quality<<<1, 1024, 0, stream>>>(boxes, scores, edgeq, mp, qual, keys);
    k_sort<<<1, 1024, 0, stream>>>(keys, boxes, order, x1s, y1s, x2s, y2s, ars);
    dim3 gmat(NW, NW);
    k_mat<<<gmat, 64, 0, stream>>>(x1s, y1s, x2s, y2s, ars, mat);
    k_scan<<<1, 64, 0, stream>>>(mat, keepm);
    k_out<<<NB / 256, 256, 0, stream>>>(boxes, scores, qual, order, keepm, labels, out);
}

// Round 2
// 377.217 us; speedup vs baseline: 2.7140x; 2.7140x over previous
//
#include <hip/hip_runtime.h>

#pragma clang fp contract(off)

typedef unsigned long long u64;
typedef unsigned int u32;
typedef unsigned short u16;

#define NB 8192
#define NW 128          // NB/64 suppression words
#define CAP 64          // max stored neighbors per row

// workspace layout (bytes)
#define OFF_KEYS  0                        // u64[NB]
#define OFF_ORDER (OFF_KEYS  + NB * 8)     // int[NB]
#define OFF_EDGE  (OFF_ORDER + NB * 4)     // float[NB]
#define OFF_MP    (OFF_EDGE  + NB * 4)     // float[NB]
#define OFF_Q     (OFF_MP    + NB * 4)     // float[NB]
#define OFF_X1    (OFF_Q     + NB * 4)
#define OFF_Y1    (OFF_X1    + NB * 4)
#define OFF_X2    (OFF_Y1    + NB * 4)
#define OFF_Y2    (OFF_X2    + NB * 4)
#define OFF_AR    (OFF_Y2    + NB * 4)
#define OFF_KEEP  (OFF_AR    + NB * 4)     // u64[NW]
#define OFF_CNT   (OFF_KEEP  + NW * 8)     // u32[NB]
#define OFF_ENT   (OFF_CNT   + NB * 4)     // u16[NB*CAP]  (1 MB)

__device__ __forceinline__ float haar3(float a, float b, float c, float d) {
    return fabsf(a + b - c - d) + fabsf(a - b + c - d) + fabsf(a - b - c + d);
}

// ---------- K1: per-box edge quality from 64x64 features ----------
__global__ __launch_bounds__(256) void k_edge(const float* __restrict__ feat,
                                              float* __restrict__ edgeq) {
    int n = blockIdx.x;
    const float* f = feat + (size_t)n * 4096;
    int t = threadIdx.x;
    int hr = t >> 3, g = t & 7;                 // haar row 0..31, group 0..7
    const float4* row0 = (const float4*)(f + (2 * hr) * 64);
    const float4* row1 = (const float4*)(f + (2 * hr) * 64 + 64);
    float4 e0 = row0[g];
    float4 e1 = row0[8 + g];
    float4 o0 = row1[g];
    float4 o1 = row1[8 + g];
    float s = haar3(e0.x, e0.y, o0.x, o0.y) + haar3(e0.z, e0.w, o0.z, o0.w)
            + haar3(e1.x, e1.y, o1.x, o1.y) + haar3(e1.z, e1.w, o1.z, o1.w);
    for (int off = 32; off; off >>= 1) s += __shfl_down(s, off, 64);
    __shared__ float wsum[4];
    int wv = t >> 6, ln = t & 63;
    if (ln == 0) wsum[wv] = s;
    __syncthreads();
    if (t == 0) edgeq[n] = (wsum[0] + wsum[1] + wsum[2] + wsum[3]) * (0.5f / 3072.0f);
}

// ---------- K2: per-row max softmax prob over 1000 logits ----------
__global__ __launch_bounds__(256) void k_logit(const float* __restrict__ logits,
                                               float* __restrict__ mp) {
    int wave = threadIdx.x >> 6, lane = threadIdx.x & 63;
    int row = blockIdx.x * 4 + wave;
    const float4* p = (const float4*)(logits + (size_t)row * 1000);
    float4 v0 = p[lane];
    float4 v1 = p[lane + 64];
    float4 v2 = p[lane + 128];
    bool has3 = (lane + 192) < 250;
    float4 v3 = p[has3 ? (lane + 192) : lane];
    float m = fmaxf(fmaxf(fmaxf(v0.x, v0.y), fmaxf(v0.z, v0.w)),
                    fmaxf(fmaxf(v1.x, v1.y), fmaxf(v1.z, v1.w)));
    m = fmaxf(m, fmaxf(fmaxf(v2.x, v2.y), fmaxf(v2.z, v2.w)));
    if (has3) m = fmaxf(m, fmaxf(fmaxf(v3.x, v3.y), fmaxf(v3.z, v3.w)));
    for (int off = 32; off; off >>= 1) m = fmaxf(m, __shfl_xor(m, off, 64));
    float s = expf(v0.x - m) + expf(v0.y - m) + expf(v0.z - m) + expf(v0.w - m)
            + expf(v1.x - m) + expf(v1.y - m) + expf(v1.z - m) + expf(v1.w - m)
            + expf(v2.x - m) + expf(v2.y - m) + expf(v2.z - m) + expf(v2.w - m);
    if (has3) s += expf(v3.x - m) + expf(v3.y - m) + expf(v3.z - m) + expf(v3.w - m);
    for (int off = 32; off; off >>= 1) s += __shfl_xor(s, off, 64);
    if (lane == 0) mp[row] = 1.0f / s;
}

// ---------- K3: quality + sort keys + zero adjacency counts ----------
__global__ __launch_bounds__(1024) void k_quality(const float* __restrict__ boxes,
        const float* __restrict__ scores, const float* __restrict__ edgeq,
        const float* __restrict__ mp, float* __restrict__ quality,
        u64* __restrict__ keys, u32* __restrict__ cnt) {
    int tid = threadIdx.x;
    #pragma unroll
    for (int t = 0; t < 8; ++t) cnt[tid + t * 1024] = 0;
    float amax = 0.f;
    float areaLoc[8];
    #pragma unroll
    for (int t = 0; t < 8; ++t) {
        int i = tid + t * 1024;
        float4 b = ((const float4*)boxes)[i];
        float w = b.z - b.x, h = b.w - b.y;
        areaLoc[t] = w * h;
        amax = fmaxf(amax, areaLoc[t]);
    }
    for (int off = 32; off; off >>= 1) amax = fmaxf(amax, __shfl_xor(amax, off, 64));
    __shared__ float wmax[16];
    int wv = tid >> 6, ln = tid & 63;
    if (ln == 0) wmax[wv] = amax;
    __syncthreads();
    if (tid == 0) {
        float mm = wmax[0];
        for (int k = 1; k < 16; ++k) mm = fmaxf(mm, wmax[k]);
        wmax[0] = mm;
    }
    __syncthreads();
    float maxA = wmax[0];
    #pragma unroll
    for (int t = 0; t < 8; ++t) {
        int i = tid + t * 1024;
        float4 b = ((const float4*)boxes)[i];
        float w = b.z - b.x, h = b.w - b.y;
        float aspect = fminf(w / h, h / w);
        float ascore = areaLoc[t] / (maxA + 1e-6f);
        ascore = fminf(fmaxf(ascore, 0.f), 1.f);
        float det = scores[i] * mp[i] * (aspect * ascore);
        float q = det * 0.4f + 0.3f + edgeq[i] * 0.3f;
        quality[i] = q;
        u32 sb = __float_as_uint(scores[i]);
        sb ^= (sb >> 31) ? 0xFFFFFFFFu : 0x80000000u;   // order-preserving flip
        keys[i] = ((u64)sb << 32) | (u64)(0xFFFFFFFFu - (u32)i);
    }
}

// ---------- K4: bitonic descending sort of 8192 u64 keys (single block) ----------
__global__ __launch_bounds__(1024) void k_sort(const u64* __restrict__ keysIn,
        const float* __restrict__ boxes, int* __restrict__ order,
        float* __restrict__ x1s, float* __restrict__ y1s,
        float* __restrict__ x2s, float* __restrict__ y2s,
        float* __restrict__ ars) {
    __shared__ u64 k[NB];
    int tid = threadIdx.x;
    #pragma unroll
    for (int t = 0; t < 8; ++t) k[tid + t * 1024] = keysIn[tid + t * 1024];
    __syncthreads();
    for (int size = 2; size <= NB; size <<= 1) {
        for (int stride = size >> 1; stride > 0; stride >>= 1) {
            #pragma unroll
            for (int t = 0; t < 4; ++t) {
                int p = tid + t * 1024;
                int i = ((p & ~(stride - 1)) << 1) | (p & (stride - 1));
                int l = i + stride;
                bool down = ((i & size) == 0);
                u64 a = k[i], b = k[l];
                bool sw = down ? (a < b) : (a > b);
                if (sw) { k[i] = b; k[l] = a; }
            }
            __syncthreads();
        }
    }
    #pragma unroll
    for (int t = 0; t < 8; ++t) {
        int i = tid + t * 1024;
        int n = (int)(0xFFFFFFFFu - (u32)(k[i] & 0xFFFFFFFFull));
        order[i] = n;
        float4 b = ((const float4*)boxes)[n];
        x1s[i] = b.x; y1s[i] = b.y; x2s[i] = b.z; y2s[i] = b.w;
        ars[i] = (b.z - b.x) * (b.w - b.y);
    }
}

// ---------- K5: sparse IoU adjacency (upper triangle), exact semantics ----------
__global__ __launch_bounds__(64) void k_mat_sparse(const float* __restrict__ x1s,
        const float* __restrict__ y1s, const float* __restrict__ x2s,
        const float* __restrict__ y2s, const float* __restrict__ ars,
        u32* __restrict__ cnt, u16* __restrict__ ent) {
    int jt = blockIdx.x, it = blockIdx.y;
    if (jt < it) return;
    int lane = threadIdx.x;
    __shared__ float cx1[64], cy1[64], cx2[64], cy2[64], car[64];
    int j0 = jt * 64;
    cx1[lane] = x1s[j0 + lane]; cy1[lane] = y1s[j0 + lane];
    cx2[lane] = x2s[j0 + lane]; cy2[lane] = y2s[j0 + lane];
    car[lane] = ars[j0 + lane];
    __syncthreads();
    int i = it * 64 + lane;
    float X1 = x1s[i], Y1 = y1s[i], X2 = x2s[i], Y2 = y2s[i], AR = ars[i];
    #pragma unroll 4
    for (int b = 0; b < 64; ++b) {
        int j = j0 + b;
        float xx1 = fmaxf(cx1[b], X1);
        float yy1 = fmaxf(cy1[b], Y1);
        float xx2 = fminf(cx2[b], X2);
        float yy2 = fminf(cy2[b], Y2);
        float iw = fmaxf(xx2 - xx1, 0.0f);
        float ih = fmaxf(yy2 - yy1, 0.0f);
        float inter = iw * ih;
        float denom = (AR + car[b]) - inter;
        // cheap prefilter: iou>0.5 implies inter > 0.25*denom (huge margin)
        if (inter > 0.25f * denom && j > i) {
            float iou = inter / denom;            // exact IEEE semantics
            if (iou > 0.5f) {
                u32 pos = atomicAdd(&cnt[i], 1u);
                if (pos < CAP) ent[(size_t)i * CAP + pos] = (u16)j;
            }
        }
    }
}

// ---------- K6: sparse greedy scan, single wave ----------
#define EXTRACT(EARR, E) ((((E) & 1) ? ((&EARR[(E) >> 3].x)[((E) >> 1) & 3] >> 16) \
                                     : ((&EARR[(E) >> 3].x)[((E) >> 1) & 3])) & 0xFFFFu)

__global__ __launch_bounds__(64) void k_scan2(const u32* __restrict__ cnt,
        const u16* __restrict__ ent, u64* __restrict__ keepm) {
    __shared__ u64 sup[NW];
    int lane = threadIdx.x;
    sup[2 * lane] = 0; sup[2 * lane + 1] = 0;
    __syncthreads();
    const uint4* entv = (const uint4*)ent;      // 8 x uint4 per row
    u32 cA; uint4 eA[8];
    u32 cB; uint4 eB[8];
    {   // load block 0 records
        int r = lane;
        cA = cnt[r];
        #pragma unroll
        for (int q = 0; q < 8; ++q) eA[q] = entv[(size_t)r * 8 + q];
    }
    for (int b = 0; b < NW; ++b) {
        if (b + 1 < NW) {                       // prefetch next block's records
            int r = (b + 1) * 64 + lane;
            cB = cnt[r];
            #pragma unroll
            for (int q = 0; q < 8; ++q) eB[q] = entv[(size_t)r * 8 + q];
        }
        u64 supw = sup[b];                      // accumulated cross-block suppression
        int myCnt = (int)min(cA, (u32)CAP);
        // in-block suppression mask for my row
        u64 mask = 0;
        #pragma unroll
        for (int e = 0; e < CAP; ++e) {
            if (e >= myCnt) break;
            u32 j = EXTRACT(eA, e);
            if ((int)(j >> 6) == b) mask |= (1ull << (j & 63));
        }
        u64 hasm = __ballot(mask != 0);
        u64 cand = ~supw;
        u64 S = cand & hasm;                    // only these can change anything
        u64 supn = 0;
        while (S) {
            int i = __builtin_ctzll(S);
            u64 m = (u64)__shfl((long long)mask, i, 64);
            supn |= m;
            S &= (S - 1);
            S &= ~supn;
        }
        u64 keptb = cand & ~supn;
        if (lane == 0) keepm[b] = keptb;
        // scatter my future-block suppressions if I'm kept
        if ((keptb >> lane) & 1ull) {
            #pragma unroll
            for (int e = 0; e < CAP; ++e) {
                if (e >= myCnt) break;
                u32 j = EXTRACT(eA, e);
                atomicOr(&sup[j >> 6], 1ull << (j & 63));
            }
        }
        __syncthreads();                        // order LDS atomics before next read
        cA = cB;
        #pragma unroll
        for (int q = 0; q < 8; ++q) eA[q] = eB[q];
    }
}

// ---------- K7: final outputs ----------
__global__ __launch_bounds__(256) void k_out(const float* __restrict__ boxes,
        const float* __restrict__ scores, const float* __restrict__ quality,
        const int* __restrict__ order, const u64* __restrict__ keepmask,
        const int* __restrict__ labels, float* __restrict__ out) {
    int i = blockIdx.x * 256 + threadIdx.x;    // sorted position
    int n = order[i];
    bool kept = (keepmask[i >> 6] >> (i & 63)) & 1ull;
    float kf = kept ? 1.0f : 0.0f;
    float4 b = ((const float4*)boxes)[n];
    float* o = out + (size_t)n * 6;
    o[0] = b.x * kf; o[1] = b.y * kf; o[2] = b.z * kf; o[3] = b.w * kf;
    o[4] = scores[n] * kf;
    o[5] = quality[n] * kf;
    out[6 * NB + n] = kf;
    out[7 * NB + n] = (float)labels[n];
}

extern "C" void kernel_launch(void* const* d_in, const int* in_sizes, int n_in,
                              void* d_out, int out_size, void* d_ws, size_t ws_size,
                              hipStream_t stream) {
    const float* boxes  = (const float*)d_in[0];
    const float* scores = (const float*)d_in[1];
    const float* logits = (const float*)d_in[2];
    const float* feats  = (const float*)d_in[3];
    const int*   labels = (const int*)d_in[4];
    float* out = (float*)d_out;
    char* ws = (char*)d_ws;

    u64*   keys   = (u64*)(ws + OFF_KEYS);
    int*   order  = (int*)(ws + OFF_ORDER);
    float* edgeq  = (float*)(ws + OFF_EDGE);
    float* mp     = (float*)(ws + OFF_MP);
    float* qual   = (float*)(ws + OFF_Q);
    float* x1s    = (float*)(ws + OFF_X1);
    float* y1s    = (float*)(ws + OFF_Y1);
    float* x2s    = (float*)(ws + OFF_X2);
    float* y2s    = (float*)(ws + OFF_Y2);
    float* ars    = (float*)(ws + OFF_AR);
    u64*   keepm  = (u64*)(ws + OFF_KEEP);
    u32*   cntArr = (u32*)(ws + OFF_CNT);
    u16*   entArr = (u16*)(ws + OFF_ENT);

    k_edge<<<NB, 256, 0, stream>>>(feats, edgeq);
    k_logit<<<NB / 4, 256, 0, stream>>>(logits, mp);
    k_quality<<<1, 1024, 0, stream>>>(boxes, scores, edgeq, mp, qual, keys, cntArr);
    k_sort<<<1, 1024, 0, stream>>>(keys, boxes, order, x1s, y1s, x2s, y2s, ars);
    dim3 gmat(NW, NW);
    k_mat_sparse<<<gmat, 64, 0, stream>>>(x1s, y1s, x2s, y2s, ars, cntArr, entArr);
    k_scan2<<<1, 64, 0, stream>>>(cntArr, entArr, keepm);
    k_out<<<NB / 256, 256, 0, stream>>>(boxes, scores, qual, order, keepm, labels, out);
}

// Round 3
// 253.355 us; speedup vs baseline: 4.0409x; 1.4889x over previous
//
#include <hip/hip_runtime.h>

#pragma clang fp contract(off)

typedef unsigned long long u64;
typedef unsigned int u32;
typedef unsigned short u16;

#define NB 8192
#define NW 128          // NB/64 suppression words
#define CAP 64          // max stored neighbors per row

// workspace layout (bytes)
#define OFF_KEYS  0                        // u64[NB]
#define OFF_ORDER (OFF_KEYS  + NB * 8)     // int[NB]
#define OFF_EDGE  (OFF_ORDER + NB * 4)     // float[NB]
#define OFF_MP    (OFF_EDGE  + NB * 4)     // float[NB]
#define OFF_Q     (OFF_MP    + NB * 4)     // float[NB]
#define OFF_X1    (OFF_Q     + NB * 4)
#define OFF_Y1    (OFF_X1    + NB * 4)
#define OFF_X2    (OFF_Y1    + NB * 4)
#define OFF_Y2    (OFF_X2    + NB * 4)
#define OFF_AR    (OFF_Y2    + NB * 4)
#define OFF_KEEP  (OFF_AR    + NB * 4)     // u64[NW]
#define OFF_CNT   (OFF_KEEP  + NW * 8)     // u32[NB]
#define OFF_ENT   (OFF_CNT   + NB * 4)     // u16[NB*CAP]  (1 MB)
#define OFF_RB    (OFF_ENT   + NB * CAP * 2) // u64[NW] row-has-edges bitmap

__device__ __forceinline__ float haar3(float a, float b, float c, float d) {
    return fabsf(a + b - c - d) + fabsf(a - b + c - d) + fabsf(a - b - c + d);
}

// ---------- K1: per-box edge quality from 64x64 features ----------
__global__ __launch_bounds__(256) void k_edge(const float* __restrict__ feat,
                                              float* __restrict__ edgeq) {
    int n = blockIdx.x;
    const float* f = feat + (size_t)n * 4096;
    int t = threadIdx.x;
    int hr = t >> 3, g = t & 7;                 // haar row 0..31, group 0..7
    const float4* row0 = (const float4*)(f + (2 * hr) * 64);
    const float4* row1 = (const float4*)(f + (2 * hr) * 64 + 64);
    float4 e0 = row0[g];
    float4 e1 = row0[8 + g];
    float4 o0 = row1[g];
    float4 o1 = row1[8 + g];
    float s = haar3(e0.x, e0.y, o0.x, o0.y) + haar3(e0.z, e0.w, o0.z, o0.w)
            + haar3(e1.x, e1.y, o1.x, o1.y) + haar3(e1.z, e1.w, o1.z, o1.w);
    for (int off = 32; off; off >>= 1) s += __shfl_down(s, off, 64);
    __shared__ float wsum[4];
    int wv = t >> 6, ln = t & 63;
    if (ln == 0) wsum[wv] = s;
    __syncthreads();
    if (t == 0) edgeq[n] = (wsum[0] + wsum[1] + wsum[2] + wsum[3]) * (0.5f / 3072.0f);
}

// ---------- K2: per-row max softmax prob over 1000 logits ----------
__global__ __launch_bounds__(256) void k_logit(const float* __restrict__ logits,
                                               float* __restrict__ mp) {
    int wave = threadIdx.x >> 6, lane = threadIdx.x & 63;
    int row = blockIdx.x * 4 + wave;
    const float4* p = (const float4*)(logits + (size_t)row * 1000);
    float4 v0 = p[lane];
    float4 v1 = p[lane + 64];
    float4 v2 = p[lane + 128];
    bool has3 = (lane + 192) < 250;
    float4 v3 = p[has3 ? (lane + 192) : lane];
    float m = fmaxf(fmaxf(fmaxf(v0.x, v0.y), fmaxf(v0.z, v0.w)),
                    fmaxf(fmaxf(v1.x, v1.y), fmaxf(v1.z, v1.w)));
    m = fmaxf(m, fmaxf(fmaxf(v2.x, v2.y), fmaxf(v2.z, v2.w)));
    if (has3) m = fmaxf(m, fmaxf(fmaxf(v3.x, v3.y), fmaxf(v3.z, v3.w)));
    for (int off = 32; off; off >>= 1) m = fmaxf(m, __shfl_xor(m, off, 64));
    float s = expf(v0.x - m) + expf(v0.y - m) + expf(v0.z - m) + expf(v0.w - m)
            + expf(v1.x - m) + expf(v1.y - m) + expf(v1.z - m) + expf(v1.w - m)
            + expf(v2.x - m) + expf(v2.y - m) + expf(v2.z - m) + expf(v2.w - m);
    if (has3) s += expf(v3.x - m) + expf(v3.y - m) + expf(v3.z - m) + expf(v3.w - m);
    for (int off = 32; off; off >>= 1) s += __shfl_xor(s, off, 64);
    if (lane == 0) mp[row] = 1.0f / s;
}

// ---------- K3: quality + sort keys + zero adjacency counts/bitmap ----------
__global__ __launch_bounds__(1024) void k_quality(const float* __restrict__ boxes,
        const float* __restrict__ scores, const float* __restrict__ edgeq,
        const float* __restrict__ mp, float* __restrict__ quality,
        u64* __restrict__ keys, u32* __restrict__ cnt, u64* __restrict__ rowbits) {
    int tid = threadIdx.x;
    #pragma unroll
    for (int t = 0; t < 8; ++t) cnt[tid + t * 1024] = 0;
    if (tid < NW) rowbits[tid] = 0;
    float amax = 0.f;
    float areaLoc[8];
    #pragma unroll
    for (int t = 0; t < 8; ++t) {
        int i = tid + t * 1024;
        float4 b = ((const float4*)boxes)[i];
        float w = b.z - b.x, h = b.w - b.y;
        areaLoc[t] = w * h;
        amax = fmaxf(amax, areaLoc[t]);
    }
    for (int off = 32; off; off >>= 1) amax = fmaxf(amax, __shfl_xor(amax, off, 64));
    __shared__ float wmax[16];
    int wv = tid >> 6, ln = tid & 63;
    if (ln == 0) wmax[wv] = amax;
    __syncthreads();
    if (tid == 0) {
        float mm = wmax[0];
        for (int k = 1; k < 16; ++k) mm = fmaxf(mm, wmax[k]);
        wmax[0] = mm;
    }
    __syncthreads();
    float maxA = wmax[0];
    #pragma unroll
    for (int t = 0; t < 8; ++t) {
        int i = tid + t * 1024;
        float4 b = ((const float4*)boxes)[i];
        float w = b.z - b.x, h = b.w - b.y;
        float aspect = fminf(w / h, h / w);
        float ascore = areaLoc[t] / (maxA + 1e-6f);
        ascore = fminf(fmaxf(ascore, 0.f), 1.f);
        float det = scores[i] * mp[i] * (aspect * ascore);
        float q = det * 0.4f + 0.3f + edgeq[i] * 0.3f;
        quality[i] = q;
        u32 sb = __float_as_uint(scores[i]);
        sb ^= (sb >> 31) ? 0xFFFFFFFFu : 0x80000000u;   // order-preserving flip
        keys[i] = ((u64)sb << 32) | (u64)(0xFFFFFFFFu - (u32)i);
    }
}

// ---------- K4: bitonic descending sort of 8192 u64 keys (single block) ----------
__global__ __launch_bounds__(1024) void k_sort(const u64* __restrict__ keysIn,
        const float* __restrict__ boxes, int* __restrict__ order,
        float* __restrict__ x1s, float* __restrict__ y1s,
        float* __restrict__ x2s, float* __restrict__ y2s,
        float* __restrict__ ars) {
    __shared__ u64 k[NB];
    int tid = threadIdx.x;
    #pragma unroll
    for (int t = 0; t < 8; ++t) k[tid + t * 1024] = keysIn[tid + t * 1024];
    __syncthreads();
    for (int size = 2; size <= NB; size <<= 1) {
        for (int stride = size >> 1; stride > 0; stride >>= 1) {
            #pragma unroll
            for (int t = 0; t < 4; ++t) {
                int p = tid + t * 1024;
                int i = ((p & ~(stride - 1)) << 1) | (p & (stride - 1));
                int l = i + stride;
                bool down = ((i & size) == 0);
                u64 a = k[i], b = k[l];
                bool sw = down ? (a < b) : (a > b);
                if (sw) { k[i] = b; k[l] = a; }
            }
            __syncthreads();
        }
    }
    #pragma unroll
    for (int t = 0; t < 8; ++t) {
        int i = tid + t * 1024;
        int n = (int)(0xFFFFFFFFu - (u32)(k[i] & 0xFFFFFFFFull));
        order[i] = n;
        float4 b = ((const float4*)boxes)[n];
        x1s[i] = b.x; y1s[i] = b.y; x2s[i] = b.z; y2s[i] = b.w;
        ars[i] = (b.z - b.x) * (b.w - b.y);
    }
}

// ---------- K5: sparse IoU adjacency (upper triangle), exact semantics ----------
__global__ __launch_bounds__(64) void k_mat_sparse(const float* __restrict__ x1s,
        const float* __restrict__ y1s, const float* __restrict__ x2s,
        const float* __restrict__ y2s, const float* __restrict__ ars,
        u32* __restrict__ cnt, u16* __restrict__ ent, u64* __restrict__ rowbits) {
    int jt = blockIdx.x, it = blockIdx.y;
    if (jt < it) return;
    int lane = threadIdx.x;
    __shared__ float cx1[64], cy1[64], cx2[64], cy2[64], car[64];
    int j0 = jt * 64;
    cx1[lane] = x1s[j0 + lane]; cy1[lane] = y1s[j0 + lane];
    cx2[lane] = x2s[j0 + lane]; cy2[lane] = y2s[j0 + lane];
    car[lane] = ars[j0 + lane];
    __syncthreads();
    int i = it * 64 + lane;
    float X1 = x1s[i], Y1 = y1s[i], X2 = x2s[i], Y2 = y2s[i], AR = ars[i];
    #pragma unroll 4
    for (int b = 0; b < 64; ++b) {
        int j = j0 + b;
        float xx1 = fmaxf(cx1[b], X1);
        float yy1 = fmaxf(cy1[b], Y1);
        float xx2 = fminf(cx2[b], X2);
        float yy2 = fminf(cy2[b], Y2);
        float iw = fmaxf(xx2 - xx1, 0.0f);
        float ih = fmaxf(yy2 - yy1, 0.0f);
        float inter = iw * ih;
        float denom = (AR + car[b]) - inter;
        // cheap prefilter: iou>0.5 implies inter > 0.25*denom (huge margin)
        if (inter > 0.25f * denom && j > i) {
            float iou = inter / denom;            // exact IEEE semantics
            if (iou > 0.5f) {
                u32 pos = atomicAdd(&cnt[i], 1u);
                if (pos < CAP) ent[(size_t)i * CAP + pos] = (u16)j;
                if (pos == 0) atomicOr(&rowbits[i >> 6], 1ull << (i & 63));
            }
        }
    }
}

// ---------- K6: sparse greedy scan, single wave, bitmap fast path ----------
#define ISSUE(C, E, B) do {                                                    \
    if ((B) < NW) {                                                            \
        int r_ = (B) * 64 + lane;                                              \
        C = cnt[r_];                                                           \
        E = entv[(size_t)r_ * (CAP / 8)];                                      \
    }                                                                          \
} while (0)

#define PROCESS(B, C, E) do {                                                  \
    if ((B) < NW) {                                                            \
        u64 supw = sup[(B)];                                                   \
        u64 w_ = ((B) & 1) ? rb1 : rb0;                                        \
        u64 ebw = (u64)__shfl((long long)w_, (B) >> 1, 64);                    \
        u64 cand = ~supw;                                                      \
        u64 act = ebw & cand;                                                  \
        u64 keptb = cand;                                                      \
        if (act) {                                                             \
            bool mine = (act >> lane) & 1ull;                                  \
            int mc = mine ? (int)min(C, (u32)CAP) : 0;                         \
            u32 jj[8];                                                         \
            jj[0] = E.x & 0xFFFFu; jj[1] = E.x >> 16;                          \
            jj[2] = E.y & 0xFFFFu; jj[3] = E.y >> 16;                          \
            jj[4] = E.z & 0xFFFFu; jj[5] = E.z >> 16;                          \
            jj[6] = E.w & 0xFFFFu; jj[7] = E.w >> 16;                          \
            u64 inmask = 0;                                                    \
            _Pragma("unroll")                                                  \
            for (int e = 0; e < 8; ++e)                                        \
                if (e < mc && (int)(jj[e] >> 6) == (B))                        \
                    inmask |= (1ull << (jj[e] & 63));                          \
            if (mc > 8) {                                                      \
                int r_ = (B) * 64 + lane;                                      \
                for (int e = 8; e < mc; ++e) {                                 \
                    u32 j = ent[(size_t)r_ * CAP + e];                         \
                    if ((int)(j >> 6) == (B)) inmask |= (1ull << (j & 63));    \
                }                                                              \
            }                                                                  \
            u64 S = __ballot(inmask != 0ull);                                  \
            u64 supn = 0;                                                      \
            while (S) {                                                        \
                int t_ = __builtin_ctzll(S);                                   \
                u64 m_ = (u64)__shfl((long long)inmask, t_, 64);               \
                supn |= m_;                                                    \
                S &= (S - 1);                                                  \
                S &= ~supn;                                                    \
            }                                                                  \
            keptb = cand & ~supn;                                              \
            if (((keptb >> lane) & 1ull) && mc > 0) {                          \
                _Pragma("unroll")                                              \
                for (int e = 0; e < 8; ++e)                                    \
                    if (e < mc)                                                \
                        atomicOr(&sup[jj[e] >> 6], 1ull << (jj[e] & 63));      \
                if (mc > 8) {                                                  \
                    int r_ = (B) * 64 + lane;                                  \
                    for (int e = 8; e < mc; ++e) {                             \
                        u32 j = ent[(size_t)r_ * CAP + e];                     \
                        atomicOr(&sup[j >> 6], 1ull << (j & 63));              \
                    }                                                          \
                }                                                              \
            }                                                                  \
            __syncthreads();                                                   \
        }                                                                      \
        if (lane == 0) keepm[(B)] = keptb;                                     \
    }                                                                          \
} while (0)

__global__ __launch_bounds__(64) void k_scan3(const u32* __restrict__ cnt,
        const u16* __restrict__ ent, const u64* __restrict__ rowbits,
        u64* __restrict__ keepm) {
    __shared__ u64 sup[NW];
    int lane = threadIdx.x;
    sup[2 * lane] = 0; sup[2 * lane + 1] = 0;
    u64 rb0 = rowbits[2 * lane];
    u64 rb1 = rowbits[2 * lane + 1];
    __syncthreads();
    const uint4* entv = (const uint4*)ent;      // 8 x uint4 per row
    u32 cA, cB, cC;
    uint4 eA, eB, eC;
    ISSUE(cA, eA, 0);
    ISSUE(cB, eB, 1);
    for (int bb = 0; bb < NW; bb += 3) {
        ISSUE(cC, eC, bb + 2);
        PROCESS(bb, cA, eA);
        ISSUE(cA, eA, bb + 3);
        PROCESS(bb + 1, cB, eB);
        ISSUE(cB, eB, bb + 4);
        PROCESS(bb + 2, cC, eC);
    }
}

// ---------- K7: final outputs ----------
__global__ __launch_bounds__(256) void k_out(const float* __restrict__ boxes,
        const float* __restrict__ scores, const float* __restrict__ quality,
        const int* __restrict__ order, const u64* __restrict__ keepmask,
        const int* __restrict__ labels, float* __restrict__ out) {
    int i = blockIdx.x * 256 + threadIdx.x;    // sorted position
    int n = order[i];
    bool kept = (keepmask[i >> 6] >> (i & 63)) & 1ull;
    float kf = kept ? 1.0f : 0.0f;
    float4 b = ((const float4*)boxes)[n];
    float* o = out + (size_t)n * 6;
    o[0] = b.x * kf; o[1] = b.y * kf; o[2] = b.z * kf; o[3] = b.w * kf;
    o[4] = scores[n] * kf;
    o[5] = quality[n] * kf;
    out[6 * NB + n] = kf;
    out[7 * NB + n] = (float)labels[n];
}

extern "C" void kernel_launch(void* const* d_in, const int* in_sizes, int n_in,
                              void* d_out, int out_size, void* d_ws, size_t ws_size,
                              hipStream_t stream) {
    const float* boxes  = (const float*)d_in[0];
    const float* scores = (const float*)d_in[1];
    const float* logits = (const float*)d_in[2];
    const float* feats  = (const float*)d_in[3];
    const int*   labels = (const int*)d_in[4];
    float* out = (float*)d_out;
    char* ws = (char*)d_ws;

    u64*   keys   = (u64*)(ws + OFF_KEYS);
    int*   order  = (int*)(ws + OFF_ORDER);
    float* edgeq  = (float*)(ws + OFF_EDGE);
    float* mp     = (float*)(ws + OFF_MP);
    float* qual   = (float*)(ws + OFF_Q);
    float* x1s    = (float*)(ws + OFF_X1);
    float* y1s    = (float*)(ws + OFF_Y1);
    float* x2s    = (float*)(ws + OFF_X2);
    float* y2s    = (float*)(ws + OFF_Y2);
    float* ars    = (float*)(ws + OFF_AR);
    u64*   keepm  = (u64*)(ws + OFF_KEEP);
    u32*   cntArr = (u32*)(ws + OFF_CNT);
    u16*   entArr = (u16*)(ws + OFF_ENT);
    u64*   rbArr  = (u64*)(ws + OFF_RB);

    k_edge<<<NB, 256, 0, stream>>>(feats, edgeq);
    k_logit<<<NB / 4, 256, 0, stream>>>(logits, mp);
    k_quality<<<1, 1024, 0, stream>>>(boxes, scores, edgeq, mp, qual, keys, cntArr, rbArr);
    k_sort<<<1, 1024, 0, stream>>>(keys, boxes, order, x1s, y1s, x2s, y2s, ars);
    dim3 gmat(NW, NW);
    k_mat_sparse<<<gmat, 64, 0, stream>>>(x1s, y1s, x2s, y2s, ars, cntArr, entArr, rbArr);
    k_scan3<<<1, 64, 0, stream>>>(cntArr, entArr, rbArr, keepm);
    k_out<<<NB / 256, 256, 0, stream>>>(boxes, scores, qual, order, keepm, labels, out);
}

// Round 4
// 121.823 us; speedup vs baseline: 8.4038x; 2.0797x over previous
//
#include <hip/hip_runtime.h>

#pragma clang fp contract(off)

typedef unsigned long long u64;
typedef unsigned int u32;

#define NB 8192
#define NW 128          // NB/64 bitmap words
#define EMAX 16384      // edge-list capacity (expect ~2-3k)

// workspace layout (bytes)
#define OFF_EDGEQ 0                          // float[NB]
#define OFF_MP    (OFF_EDGEQ + NB * 4)       // float[NB]
#define OFF_Q     (OFF_MP    + NB * 4)       // float[NB]
#define OFF_KEEP  (OFF_Q     + NB * 4)       // u64[NW]
#define OFF_ECNT  (OFF_KEEP  + NW * 8)       // u32[1] (padded)
#define OFF_EDGES (OFF_ECNT  + 256)          // u32[EMAX]

__device__ __forceinline__ float haar3(float a, float b, float c, float d) {
    return fabsf(a + b - c - d) + fabsf(a - b + c - d) + fabsf(a - b - c + d);
}

// ---------- K1: per-box edge quality from 64x64 features ----------
__global__ __launch_bounds__(256) void k_edge(const float* __restrict__ feat,
                                              float* __restrict__ edgeq) {
    int n = blockIdx.x;
    const float* f = feat + (size_t)n * 4096;
    int t = threadIdx.x;
    int hr = t >> 3, g = t & 7;                 // haar row 0..31, group 0..7
    const float4* row0 = (const float4*)(f + (2 * hr) * 64);
    const float4* row1 = (const float4*)(f + (2 * hr) * 64 + 64);
    float4 e0 = row0[g];
    float4 e1 = row0[8 + g];
    float4 o0 = row1[g];
    float4 o1 = row1[8 + g];
    float s = haar3(e0.x, e0.y, o0.x, o0.y) + haar3(e0.z, e0.w, o0.z, o0.w)
            + haar3(e1.x, e1.y, o1.x, o1.y) + haar3(e1.z, e1.w, o1.z, o1.w);
    for (int off = 32; off; off >>= 1) s += __shfl_down(s, off, 64);
    __shared__ float wsum[4];
    int wv = t >> 6, ln = t & 63;
    if (ln == 0) wsum[wv] = s;
    __syncthreads();
    if (t == 0) edgeq[n] = (wsum[0] + wsum[1] + wsum[2] + wsum[3]) * (0.5f / 3072.0f);
}

// ---------- K2: per-row max softmax prob over 1000 logits ----------
__global__ __launch_bounds__(256) void k_logit(const float* __restrict__ logits,
                                               float* __restrict__ mp) {
    int wave = threadIdx.x >> 6, lane = threadIdx.x & 63;
    int row = blockIdx.x * 4 + wave;
    const float4* p = (const float4*)(logits + (size_t)row * 1000);
    float4 v0 = p[lane];
    float4 v1 = p[lane + 64];
    float4 v2 = p[lane + 128];
    bool has3 = (lane + 192) < 250;
    float4 v3 = p[has3 ? (lane + 192) : lane];
    float m = fmaxf(fmaxf(fmaxf(v0.x, v0.y), fmaxf(v0.z, v0.w)),
                    fmaxf(fmaxf(v1.x, v1.y), fmaxf(v1.z, v1.w)));
    m = fmaxf(m, fmaxf(fmaxf(v2.x, v2.y), fmaxf(v2.z, v2.w)));
    if (has3) m = fmaxf(m, fmaxf(fmaxf(v3.x, v3.y), fmaxf(v3.z, v3.w)));
    for (int off = 32; off; off >>= 1) m = fmaxf(m, __shfl_xor(m, off, 64));
    float s = expf(v0.x - m) + expf(v0.y - m) + expf(v0.z - m) + expf(v0.w - m)
            + expf(v1.x - m) + expf(v1.y - m) + expf(v1.z - m) + expf(v1.w - m)
            + expf(v2.x - m) + expf(v2.y - m) + expf(v2.z - m) + expf(v2.w - m);
    if (has3) s += expf(v3.x - m) + expf(v3.y - m) + expf(v3.z - m) + expf(v3.w - m);
    for (int off = 32; off; off >>= 1) s += __shfl_xor(s, off, 64);
    if (lane == 0) mp[row] = 1.0f / s;
}

// ---------- K3: quality + zero edge counter (single block) ----------
__global__ __launch_bounds__(1024) void k_quality(const float* __restrict__ boxes,
        const float* __restrict__ scores, const float* __restrict__ edgeq,
        const float* __restrict__ mp, float* __restrict__ quality,
        u32* __restrict__ ecnt) {
    int tid = threadIdx.x;
    if (tid == 0) *ecnt = 0;
    float amax = 0.f;
    float areaLoc[8];
    #pragma unroll
    for (int t = 0; t < 8; ++t) {
        int i = tid + t * 1024;
        float4 b = ((const float4*)boxes)[i];
        float w = b.z - b.x, h = b.w - b.y;
        areaLoc[t] = w * h;
        amax = fmaxf(amax, areaLoc[t]);
    }
    for (int off = 32; off; off >>= 1) amax = fmaxf(amax, __shfl_xor(amax, off, 64));
    __shared__ float wmax[16];
    int wv = tid >> 6, ln = tid & 63;
    if (ln == 0) wmax[wv] = amax;
    __syncthreads();
    if (tid == 0) {
        float mm = wmax[0];
        for (int k = 1; k < 16; ++k) mm = fmaxf(mm, wmax[k]);
        wmax[0] = mm;
    }
    __syncthreads();
    float maxA = wmax[0];
    #pragma unroll
    for (int t = 0; t < 8; ++t) {
        int i = tid + t * 1024;
        float4 b = ((const float4*)boxes)[i];
        float w = b.z - b.x, h = b.w - b.y;
        float aspect = fminf(w / h, h / w);
        float ascore = areaLoc[t] / (maxA + 1e-6f);
        ascore = fminf(fmaxf(ascore, 0.f), 1.f);
        float det = scores[i] * mp[i] * (aspect * ascore);
        quality[i] = det * 0.4f + 0.3f + edgeq[i] * 0.3f;
    }
}

// ---------- K4: sparse IoU edge list on ORIGINAL indices ----------
__global__ __launch_bounds__(64) void k_mat(const float* __restrict__ boxes,
        const float* __restrict__ scores, u32* __restrict__ ecnt,
        u32* __restrict__ edges) {
    int jt = blockIdx.x, it = blockIdx.y;
    if (jt < it) return;
    int lane = threadIdx.x;
    __shared__ float cx1[64], cy1[64], cx2[64], cy2[64], car[64], csc[64];
    int j0 = jt * 64;
    {
        float4 bj = ((const float4*)boxes)[j0 + lane];
        cx1[lane] = bj.x; cy1[lane] = bj.y; cx2[lane] = bj.z; cy2[lane] = bj.w;
        car[lane] = (bj.z - bj.x) * (bj.w - bj.y);
        csc[lane] = scores[j0 + lane];
    }
    __syncthreads();
    int i = it * 64 + lane;
    float4 bi = ((const float4*)boxes)[i];
    float X1 = bi.x, Y1 = bi.y, X2 = bi.z, Y2 = bi.w;
    float AR = (bi.z - bi.x) * (bi.w - bi.y);
    float SI = scores[i];
    bool diag = (jt == it);
    #pragma unroll 4
    for (int b = 0; b < 64; ++b) {
        if (diag && b <= lane) continue;
        float xx1 = fmaxf(cx1[b], X1);
        float yy1 = fmaxf(cy1[b], Y1);
        float xx2 = fminf(cx2[b], X2);
        float yy2 = fminf(cy2[b], Y2);
        float iw = fmaxf(xx2 - xx1, 0.0f);
        float ih = fmaxf(yy2 - yy1, 0.0f);
        float inter = iw * ih;
        float denom = (AR + car[b]) - inter;
        // prefilter: iou>0.5 implies inter > 0.25*denom (0.25*denom exact scaling)
        if (inter > 0.25f * denom) {
            float iou = inter / denom;            // exact IEEE semantics
            if (iou > 0.5f) {
                int j = j0 + b;
                float SJ = csc[b];
                // priority: higher score wins; tie -> smaller original index
                bool ihi = (SI > SJ) || (SI == SJ && i < j);
                u32 hi = ihi ? (u32)i : (u32)j;
                u32 lo = ihi ? (u32)j : (u32)i;
                u32 pos = atomicAdd(ecnt, 1u);
                if (pos < EMAX) edges[pos] = (hi << 16) | lo;
            }
        }
    }
}

// ---------- K5: round-based greedy NMS fixed point ----------
__global__ __launch_bounds__(256) void k_scan4(const u32* __restrict__ ecnt,
        const u32* __restrict__ edges, u64* __restrict__ keepm) {
    __shared__ u64 dec[NW], kept[NW], keptIn[NW], pendIn[NW];
    __shared__ int undec;
    int tid = threadIdx.x;
    if (tid < NW) { dec[tid] = 0; kept[tid] = 0; }
    int E = (int)min(*ecnt, (u32)EMAX);
    __syncthreads();
    for (int round = 0; round < NB; ++round) {
        if (tid < NW) { keptIn[tid] = 0; pendIn[tid] = 0; }
        if (tid == 0) undec = 0;
        __syncthreads();
        for (int e = tid; e < E; e += 256) {
            u32 pk = edges[e];
            int hi = (int)(pk >> 16), lo = (int)(pk & 0xFFFFu);
            bool d = (dec[hi >> 6] >> (hi & 63)) & 1ull;
            bool k = (kept[hi >> 6] >> (hi & 63)) & 1ull;
            if (!d)     atomicOr(&pendIn[lo >> 6], 1ull << (lo & 63));
            else if (k) atomicOr(&keptIn[lo >> 6], 1ull << (lo & 63));
        }
        __syncthreads();
        if (tid < NW) {
            u64 und = ~dec[tid];
            u64 sup = und & keptIn[tid];
            u64 kp  = und & ~keptIn[tid] & ~pendIn[tid];
            kept[tid] |= kp;
            dec[tid]  |= sup | kp;
            if (und & ~(sup | kp)) undec = 1;
        }
        __syncthreads();
        if (!undec) break;
    }
    if (tid < NW) keepm[tid] = kept[tid];
}

// ---------- K6: final outputs (original index space) ----------
__global__ __launch_bounds__(256) void k_out(const float* __restrict__ boxes,
        const float* __restrict__ scores, const float* __restrict__ quality,
        const u64* __restrict__ keepmask, const int* __restrict__ labels,
        float* __restrict__ out) {
    int n = blockIdx.x * 256 + threadIdx.x;
    bool kept = (keepmask[n >> 6] >> (n & 63)) & 1ull;
    float kf = kept ? 1.0f : 0.0f;
    float4 b = ((const float4*)boxes)[n];
    float* o = out + (size_t)n * 6;
    o[0] = b.x * kf; o[1] = b.y * kf; o[2] = b.z * kf; o[3] = b.w * kf;
    o[4] = scores[n] * kf;
    o[5] = quality[n] * kf;
    out[6 * NB + n] = kf;
    out[7 * NB + n] = (float)labels[n];
}

extern "C" void kernel_launch(void* const* d_in, const int* in_sizes, int n_in,
                              void* d_out, int out_size, void* d_ws, size_t ws_size,
                              hipStream_t stream) {
    const float* boxes  = (const float*)d_in[0];
    const float* scores = (const float*)d_in[1];
    const float* logits = (const float*)d_in[2];
    const float* feats  = (const float*)d_in[3];
    const int*   labels = (const int*)d_in[4];
    float* out = (float*)d_out;
    char* ws = (char*)d_ws;

    float* edgeq  = (float*)(ws + OFF_EDGEQ);
    float* mp     = (float*)(ws + OFF_MP);
    float* qual   = (float*)(ws + OFF_Q);
    u64*   keepm  = (u64*)(ws + OFF_KEEP);
    u32*   ecnt   = (u32*)(ws + OFF_ECNT);
    u32*   edges  = (u32*)(ws + OFF_EDGES);

    k_edge<<<NB, 256, 0, stream>>>(feats, edgeq);
    k_logit<<<NB / 4, 256, 0, stream>>>(logits, mp);
    k_quality<<<1, 1024, 0, stream>>>(boxes, scores, edgeq, mp, qual, ecnt);
    dim3 gmat(NW, NW);
    k_mat<<<gmat, 64, 0, stream>>>(boxes, scores, ecnt, edges);
    k_scan4<<<1, 256, 0, stream>>>(ecnt, edges, keepm);
    k_out<<<NB / 256, 256, 0, stream>>>(boxes, scores, qual, keepm, labels, out);
}

// Round 6
// 121.261 us; speedup vs baseline: 8.4427x; 1.0046x over previous
//
#include <hip/hip_runtime.h>

#pragma clang fp contract(off)

typedef unsigned long long u64;
typedef unsigned int u32;
typedef float f32x4 __attribute__((ext_vector_type(4)));

#define NB 8192
#define NW 128          // NB/64 bitmap words
#define EMAX 16384      // edge-list capacity (expect ~2-3k)
#define ELDS 12288      // edges cached in LDS by k_scan4

// workspace layout (bytes)
#define OFF_EDGEQ 0                          // float[NB]
#define OFF_MP    (OFF_EDGEQ + NB * 4)       // float[NB]
#define OFF_Q     (OFF_MP    + NB * 4)       // float[NB]
#define OFF_KEEP  (OFF_Q     + NB * 4)       // u64[NW]
#define OFF_ECNT  (OFF_KEEP  + NW * 8)       // u32[1] (padded)
#define OFF_EDGES (OFF_ECNT  + 256)          // u32[EMAX]

__device__ __forceinline__ float4 ldnt4(const float4* p) {
    f32x4 v = __builtin_nontemporal_load((const f32x4*)p);
    return make_float4(v.x, v.y, v.z, v.w);
}

__device__ __forceinline__ float haar3(float a, float b, float c, float d) {
    return fabsf(a + b - c - d) + fabsf(a - b + c - d) + fabsf(a - b - c + d);
}

// ---------- K1: per-box edge quality from 64x64 features ----------
__global__ __launch_bounds__(256) void k_edge(const float* __restrict__ feat,
                                              float* __restrict__ edgeq) {
    int n = blockIdx.x;
    const float* f = feat + (size_t)n * 4096;
    int t = threadIdx.x;
    int hr = t >> 3, g = t & 7;                 // haar row 0..31, group 0..7
    const float4* row0 = (const float4*)(f + (2 * hr) * 64);
    const float4* row1 = (const float4*)(f + (2 * hr) * 64 + 64);
    float4 e0 = ldnt4(row0 + g);
    float4 e1 = ldnt4(row0 + 8 + g);
    float4 o0 = ldnt4(row1 + g);
    float4 o1 = ldnt4(row1 + 8 + g);
    float s = haar3(e0.x, e0.y, o0.x, o0.y) + haar3(e0.z, e0.w, o0.z, o0.w)
            + haar3(e1.x, e1.y, o1.x, o1.y) + haar3(e1.z, e1.w, o1.z, o1.w);
    for (int off = 32; off; off >>= 1) s += __shfl_down(s, off, 64);
    __shared__ float wsum[4];
    int wv = t >> 6, ln = t & 63;
    if (ln == 0) wsum[wv] = s;
    __syncthreads();
    if (t == 0) edgeq[n] = (wsum[0] + wsum[1] + wsum[2] + wsum[3]) * (0.5f / 3072.0f);
}

// ---------- K2: per-row max softmax prob over 1000 logits ----------
__global__ __launch_bounds__(256) void k_logit(const float* __restrict__ logits,
                                               float* __restrict__ mp) {
    int wave = threadIdx.x >> 6, lane = threadIdx.x & 63;
    int row = blockIdx.x * 4 + wave;
    const float4* p = (const float4*)(logits + (size_t)row * 1000);
    float4 v0 = ldnt4(p + lane);
    float4 v1 = ldnt4(p + lane + 64);
    float4 v2 = ldnt4(p + lane + 128);
    bool has3 = (lane + 192) < 250;
    float4 v3 = ldnt4(p + (has3 ? (lane + 192) : lane));
    float m = fmaxf(fmaxf(fmaxf(v0.x, v0.y), fmaxf(v0.z, v0.w)),
                    fmaxf(fmaxf(v1.x, v1.y), fmaxf(v1.z, v1.w)));
    m = fmaxf(m, fmaxf(fmaxf(v2.x, v2.y), fmaxf(v2.z, v2.w)));
    if (has3) m = fmaxf(m, fmaxf(fmaxf(v3.x, v3.y), fmaxf(v3.z, v3.w)));
    for (int off = 32; off; off >>= 1) m = fmaxf(m, __shfl_xor(m, off, 64));
    float s = __expf(v0.x - m) + __expf(v0.y - m) + __expf(v0.z - m) + __expf(v0.w - m)
            + __expf(v1.x - m) + __expf(v1.y - m) + __expf(v1.z - m) + __expf(v1.w - m)
            + __expf(v2.x - m) + __expf(v2.y - m) + __expf(v2.z - m) + __expf(v2.w - m);
    if (has3) s += __expf(v3.x - m) + __expf(v3.y - m) + __expf(v3.z - m) + __expf(v3.w - m);
    for (int off = 32; off; off >>= 1) s += __shfl_xor(s, off, 64);
    if (lane == 0) mp[row] = 1.0f / s;
}

// ---------- K3: quality + zero edge counter (single block) ----------
__global__ __launch_bounds__(1024) void k_quality(const float* __restrict__ boxes,
        const float* __restrict__ scores, const float* __restrict__ edgeq,
        const float* __restrict__ mp, float* __restrict__ quality,
        u32* __restrict__ ecnt) {
    int tid = threadIdx.x;
    if (tid == 0) *ecnt = 0;
    float amax = 0.f;
    float areaLoc[8], aspLoc[8];
    #pragma unroll
    for (int t = 0; t < 8; ++t) {
        int i = tid + t * 1024;
        float4 b = ((const float4*)boxes)[i];
        float w = b.z - b.x, h = b.w - b.y;
        areaLoc[t] = w * h;
        aspLoc[t] = fminf(w / h, h / w);
        amax = fmaxf(amax, areaLoc[t]);
    }
    for (int off = 32; off; off >>= 1) amax = fmaxf(amax, __shfl_xor(amax, off, 64));
    __shared__ float wmax[16];
    int wv = tid >> 6, ln = tid & 63;
    if (ln == 0) wmax[wv] = amax;
    __syncthreads();
    if (tid == 0) {
        float mm = wmax[0];
        for (int k = 1; k < 16; ++k) mm = fmaxf(mm, wmax[k]);
        wmax[0] = mm;
    }
    __syncthreads();
    float maxA = wmax[0];
    #pragma unroll
    for (int t = 0; t < 8; ++t) {
        int i = tid + t * 1024;
        float ascore = areaLoc[t] / (maxA + 1e-6f);
        ascore = fminf(fmaxf(ascore, 0.f), 1.f);
        float det = scores[i] * mp[i] * (aspLoc[t] * ascore);
        quality[i] = det * 0.4f + 0.3f + edgeq[i] * 0.3f;
    }
}

// ---------- K4: sparse IoU edge list on ORIGINAL indices (4 waves/block) ----------
__global__ __launch_bounds__(256) void k_mat(const float* __restrict__ boxes,
        const float* __restrict__ scores, u32* __restrict__ ecnt,
        u32* __restrict__ edges) {
    int it = blockIdx.y;
    if ((int)blockIdx.x * 4 + 3 < it) return;        // uniform: whole block dead
    int wv = threadIdx.x >> 6, lane = threadIdx.x & 63;
    int jt = blockIdx.x * 4 + wv;
    bool active = (jt >= it);
    __shared__ float sh[4][6][64];
    if (active) {
        int j0 = jt * 64;
        float4 bj = ((const float4*)boxes)[j0 + lane];
        sh[wv][0][lane] = bj.x; sh[wv][1][lane] = bj.y;
        sh[wv][2][lane] = bj.z; sh[wv][3][lane] = bj.w;
        sh[wv][4][lane] = (bj.z - bj.x) * (bj.w - bj.y);
        sh[wv][5][lane] = scores[j0 + lane];
    }
    __syncthreads();
    if (!active) return;
    int j0 = jt * 64;
    int i = it * 64 + lane;
    float4 bi = ((const float4*)boxes)[i];
    float X1 = bi.x, Y1 = bi.y, X2 = bi.z, Y2 = bi.w;
    float AR = (bi.z - bi.x) * (bi.w - bi.y);
    float SI = scores[i];
    bool diag = (jt == it);
    #pragma unroll 4
    for (int b = 0; b < 64; ++b) {
        if (diag && b <= lane) continue;
        float xx1 = fmaxf(sh[wv][0][b], X1);
        float yy1 = fmaxf(sh[wv][1][b], Y1);
        float xx2 = fminf(sh[wv][2][b], X2);
        float yy2 = fminf(sh[wv][3][b], Y2);
        float iw = fmaxf(xx2 - xx1, 0.0f);
        float ih = fmaxf(yy2 - yy1, 0.0f);
        float inter = iw * ih;
        float denom = (AR + sh[wv][4][b]) - inter;
        // prefilter: iou>0.5 implies inter > 0.25*denom (huge margin)
        if (inter > 0.25f * denom) {
            float iou = inter / denom;            // exact IEEE semantics
            if (iou > 0.5f) {
                int j = j0 + b;
                float SJ = sh[wv][5][b];
                // priority: higher score wins; tie -> smaller original index
                bool ihi = (SI > SJ) || (SI == SJ && i < j);
                u32 hi = ihi ? (u32)i : (u32)j;
                u32 lo = ihi ? (u32)j : (u32)i;
                u32 pos = atomicAdd(ecnt, 1u);
                if (pos < EMAX) edges[pos] = (hi << 16) | lo;
            }
        }
    }
}

// ---------- K5: round-based greedy NMS fixed point (edges cached in LDS) ----------
__global__ __launch_bounds__(256) void k_scan4(const u32* __restrict__ ecnt,
        const u32* __restrict__ edges, u64* __restrict__ keepm) {
    __shared__ u64 dec[NW], kept[NW], keptIn[NW], pendIn[NW];
    __shared__ u32 eL[ELDS];
    __shared__ int undec;
    int tid = threadIdx.x;
    int E = (int)min(*ecnt, (u32)EMAX);
    if (tid < NW) { dec[tid] = 0; kept[tid] = 0; }
    for (int e = tid; e < E && e < ELDS; e += 256) eL[e] = edges[e];
    __syncthreads();
    for (int round = 0; round < NB; ++round) {
        if (tid < NW) { keptIn[tid] = 0; pendIn[tid] = 0; }
        if (tid == 0) undec = 0;
        __syncthreads();
        for (int e = tid; e < E; e += 256) {
            u32 pk = (e < ELDS) ? eL[e] : edges[e];
            int hi = (int)(pk >> 16), lo = (int)(pk & 0xFFFFu);
            bool d = (dec[hi >> 6] >> (hi & 63)) & 1ull;
            bool k = (kept[hi >> 6] >> (hi & 63)) & 1ull;
            if (!d)     atomicOr(&pendIn[lo >> 6], 1ull << (lo & 63));
            else if (k) atomicOr(&keptIn[lo >> 6], 1ull << (lo & 63));
        }
        __syncthreads();
        if (tid < NW) {
            u64 und = ~dec[tid];
            u64 sup = und & keptIn[tid];
            u64 kp  = und & ~keptIn[tid] & ~pendIn[tid];
            kept[tid] |= kp;
            dec[tid]  |= sup | kp;
            if (und & ~(sup | kp)) undec = 1;
        }
        __syncthreads();
        if (!undec) break;
    }
    if (tid < NW) keepm[tid] = kept[tid];
}

// ---------- K6: final outputs (original index space) ----------
__global__ __launch_bounds__(256) void k_out(const float* __restrict__ boxes,
        const float* __restrict__ scores, const float* __restrict__ quality,
        const u64* __restrict__ keepmask, const int* __restrict__ labels,
        float* __restrict__ out) {
    int n = blockIdx.x * 256 + threadIdx.x;
    bool kept = (keepmask[n >> 6] >> (n & 63)) & 1ull;
    float kf = kept ? 1.0f : 0.0f;
    float4 b = ((const float4*)boxes)[n];
    float* o = out + (size_t)n * 6;
    o[0] = b.x * kf; o[1] = b.y * kf; o[2] = b.z * kf; o[3] = b.w * kf;
    o[4] = scores[n] * kf;
    o[5] = quality[n] * kf;
    out[6 * NB + n] = kf;
    out[7 * NB + n] = (float)labels[n];
}

extern "C" void kernel_launch(void* const* d_in, const int* in_sizes, int n_in,
                              void* d_out, int out_size, void* d_ws, size_t ws_size,
                              hipStream_t stream) {
    const float* boxes  = (const float*)d_in[0];
    const float* scores = (const float*)d_in[1];
    const float* logits = (const float*)d_in[2];
    const float* feats  = (const float*)d_in[3];
    const int*   labels = (const int*)d_in[4];
    float* out = (float*)d_out;
    char* ws = (char*)d_ws;

    float* edgeq  = (float*)(ws + OFF_EDGEQ);
    float* mp     = (float*)(ws + OFF_MP);
    float* qual   = (float*)(ws + OFF_Q);
    u64*   keepm  = (u64*)(ws + OFF_KEEP);
    u32*   ecnt   = (u32*)(ws + OFF_ECNT);
    u32*   edges  = (u32*)(ws + OFF_EDGES);

    k_edge<<<NB, 256, 0, stream>>>(feats, edgeq);
    k_logit<<<NB / 4, 256, 0, stream>>>(logits, mp);
    k_quality<<<1, 1024, 0, stream>>>(boxes, scores, edgeq, mp, qual, ecnt);
    dim3 gmat(32, NW);
    k_mat<<<gmat, 256, 0, stream>>>(boxes, scores, ecnt, edges);
    k_scan4<<<1, 256, 0, stream>>>(ecnt, edges, keepm);
    k_out<<<NB / 256, 256, 0, stream>>>(boxes, scores, qual, keepm, labels, out);
}

// Round 7
// 116.517 us; speedup vs baseline: 8.7865x; 1.0407x over previous
//
#include <hip/hip_runtime.h>

#pragma clang fp contract(off)

typedef unsigned long long u64;
typedef unsigned int u32;
typedef float f32x4 __attribute__((ext_vector_type(4)));

#define NB 8192
#define NW 128          // NB/64 bitmap words
#define EMAX 16384      // edge-list capacity (expect ~2-3k)
#define ELDS 12288      // edges cached in LDS by k_scan4

// workspace layout (bytes)
#define OFF_EDGEQ 0                          // float[NB]
#define OFF_MP    (OFF_EDGEQ + NB * 4)       // float[NB]
#define OFF_KEEP  (OFF_MP    + NB * 4)       // u64[NW]
#define OFF_ECNT  (OFF_KEEP  + NW * 8)       // u32[1]
#define OFF_MAXA  (OFF_ECNT  + 64)           // u32[1] (float bits)
#define OFF_EDGES (OFF_MAXA  + 192)          // u32[EMAX]

__device__ __forceinline__ float4 ldnt4(const float4* p) {
    f32x4 v = __builtin_nontemporal_load((const f32x4*)p);
    return make_float4(v.x, v.y, v.z, v.w);
}

__device__ __forceinline__ float haar3(float a, float b, float c, float d) {
    return fabsf(a + b - c - d) + fabsf(a - b + c - d) + fabsf(a - b - c + d);
}

// ---------- K1: per-box edge quality from 64x64 features (+init counters) ----------
__global__ __launch_bounds__(256) void k_edge(const float* __restrict__ feat,
                                              float* __restrict__ edgeq,
                                              u32* __restrict__ ecnt,
                                              u32* __restrict__ maxab) {
    int n = blockIdx.x;
    int t = threadIdx.x;
    if (n == 0 && t == 0) { *ecnt = 0; *maxab = 0; }
    const float* f = feat + (size_t)n * 4096;
    int hr = t >> 3, g = t & 7;                 // haar row 0..31, group 0..7
    const float4* row0 = (const float4*)(f + (2 * hr) * 64);
    const float4* row1 = (const float4*)(f + (2 * hr) * 64 + 64);
    float4 e0 = ldnt4(row0 + g);
    float4 e1 = ldnt4(row0 + 8 + g);
    float4 o0 = ldnt4(row1 + g);
    float4 o1 = ldnt4(row1 + 8 + g);
    float s = haar3(e0.x, e0.y, o0.x, o0.y) + haar3(e0.z, e0.w, o0.z, o0.w)
            + haar3(e1.x, e1.y, o1.x, o1.y) + haar3(e1.z, e1.w, o1.z, o1.w);
    for (int off = 32; off; off >>= 1) s += __shfl_down(s, off, 64);
    __shared__ float wsum[4];
    int wv = t >> 6, ln = t & 63;
    if (ln == 0) wsum[wv] = s;
    __syncthreads();
    if (t == 0) edgeq[n] = (wsum[0] + wsum[1] + wsum[2] + wsum[3]) * (0.5f / 3072.0f);
}

// ---------- K2: per-row max softmax prob over 1000 logits ----------
__global__ __launch_bounds__(256) void k_logit(const float* __restrict__ logits,
                                               float* __restrict__ mp) {
    int wave = threadIdx.x >> 6, lane = threadIdx.x & 63;
    int row = blockIdx.x * 4 + wave;
    const float4* p = (const float4*)(logits + (size_t)row * 1000);
    float4 v0 = ldnt4(p + lane);
    float4 v1 = ldnt4(p + lane + 64);
    float4 v2 = ldnt4(p + lane + 128);
    bool has3 = (lane + 192) < 250;
    float4 v3 = ldnt4(p + (has3 ? (lane + 192) : lane));
    float m = fmaxf(fmaxf(fmaxf(v0.x, v0.y), fmaxf(v0.z, v0.w)),
                    fmaxf(fmaxf(v1.x, v1.y), fmaxf(v1.z, v1.w)));
    m = fmaxf(m, fmaxf(fmaxf(v2.x, v2.y), fmaxf(v2.z, v2.w)));
    if (has3) m = fmaxf(m, fmaxf(fmaxf(v3.x, v3.y), fmaxf(v3.z, v3.w)));
    for (int off = 32; off; off >>= 1) m = fmaxf(m, __shfl_xor(m, off, 64));
    float s = __expf(v0.x - m) + __expf(v0.y - m) + __expf(v0.z - m) + __expf(v0.w - m)
            + __expf(v1.x - m) + __expf(v1.y - m) + __expf(v1.z - m) + __expf(v1.w - m)
            + __expf(v2.x - m) + __expf(v2.y - m) + __expf(v2.z - m) + __expf(v2.w - m);
    if (has3) s += __expf(v3.x - m) + __expf(v3.y - m) + __expf(v3.z - m) + __expf(v3.w - m);
    for (int off = 32; off; off >>= 1) s += __shfl_xor(s, off, 64);
    if (lane == 0) mp[row] = 1.0f / s;
}

// ---------- K3: sparse IoU edge list + global max-area (diag waves) ----------
__global__ __launch_bounds__(256) void k_mat(const float* __restrict__ boxes,
        const float* __restrict__ scores, u32* __restrict__ ecnt,
        u32* __restrict__ edges, u32* __restrict__ maxab) {
    int it = blockIdx.y;
    if ((int)blockIdx.x * 4 + 3 < it) return;        // uniform: whole block dead
    int wv = threadIdx.x >> 6, lane = threadIdx.x & 63;
    int jt = blockIdx.x * 4 + wv;
    bool active = (jt >= it);
    __shared__ float sh[4][6][64];
    if (active) {
        int j0 = jt * 64;
        float4 bj = ((const float4*)boxes)[j0 + lane];
        sh[wv][0][lane] = bj.x; sh[wv][1][lane] = bj.y;
        sh[wv][2][lane] = bj.z; sh[wv][3][lane] = bj.w;
        sh[wv][4][lane] = (bj.z - bj.x) * (bj.w - bj.y);
        sh[wv][5][lane] = scores[j0 + lane];
    }
    __syncthreads();
    if (!active) return;
    int j0 = jt * 64;
    int i = it * 64 + lane;
    float4 bi = ((const float4*)boxes)[i];
    float X1 = bi.x, Y1 = bi.y, X2 = bi.z, Y2 = bi.w;
    float AR = (bi.z - bi.x) * (bi.w - bi.y);
    float SI = scores[i];
    bool diag = (jt == it);
    if (diag) {                                      // exactly one wave per tile
        float am = AR;
        for (int off = 32; off; off >>= 1) am = fmaxf(am, __shfl_xor(am, off, 64));
        if (lane == 0) atomicMax(maxab, __float_as_uint(am));  // positive floats: bit-monotone
    }
    #pragma unroll 4
    for (int b = 0; b < 64; ++b) {
        if (diag && b <= lane) continue;
        float xx1 = fmaxf(sh[wv][0][b], X1);
        float yy1 = fmaxf(sh[wv][1][b], Y1);
        float xx2 = fminf(sh[wv][2][b], X2);
        float yy2 = fminf(sh[wv][3][b], Y2);
        float iw = fmaxf(xx2 - xx1, 0.0f);
        float ih = fmaxf(yy2 - yy1, 0.0f);
        float inter = iw * ih;
        float denom = (AR + sh[wv][4][b]) - inter;
        // prefilter: iou>0.5 implies inter > 0.25*denom (huge margin)
        if (inter > 0.25f * denom) {
            float iou = inter / denom;            // exact IEEE semantics
            if (iou > 0.5f) {
                int j = j0 + b;
                float SJ = sh[wv][5][b];
                // priority: higher score wins; tie -> smaller original index
                bool ihi = (SI > SJ) || (SI == SJ && i < j);
                u32 hi = ihi ? (u32)i : (u32)j;
                u32 lo = ihi ? (u32)j : (u32)i;
                u32 pos = atomicAdd(ecnt, 1u);
                if (pos < EMAX) edges[pos] = (hi << 16) | lo;
            }
        }
    }
}

// ---------- K4: round-based greedy NMS fixed point (edges cached in LDS) ----------
__global__ __launch_bounds__(256) void k_scan4(const u32* __restrict__ ecnt,
        const u32* __restrict__ edges, u64* __restrict__ keepm) {
    __shared__ u64 dec[NW], kept[NW], keptIn[NW], pendIn[NW];
    __shared__ u32 eL[ELDS];
    __shared__ int undec;
    int tid = threadIdx.x;
    int E = (int)min(*ecnt, (u32)EMAX);
    if (tid < NW) { dec[tid] = 0; kept[tid] = 0; }
    for (int e = tid; e < E && e < ELDS; e += 256) eL[e] = edges[e];
    __syncthreads();
    for (int round = 0; round < NB; ++round) {
        if (tid < NW) { keptIn[tid] = 0; pendIn[tid] = 0; }
        if (tid == 0) undec = 0;
        __syncthreads();
        for (int e = tid; e < E; e += 256) {
            u32 pk = (e < ELDS) ? eL[e] : edges[e];
            int hi = (int)(pk >> 16), lo = (int)(pk & 0xFFFFu);
            bool d = (dec[hi >> 6] >> (hi & 63)) & 1ull;
            bool k = (kept[hi >> 6] >> (hi & 63)) & 1ull;
            if (!d)     atomicOr(&pendIn[lo >> 6], 1ull << (lo & 63));
            else if (k) atomicOr(&keptIn[lo >> 6], 1ull << (lo & 63));
        }
        __syncthreads();
        if (tid < NW) {
            u64 und = ~dec[tid];
            u64 sup = und & keptIn[tid];
            u64 kp  = und & ~keptIn[tid] & ~pendIn[tid];
            kept[tid] |= kp;
            dec[tid]  |= sup | kp;
            if (und & ~(sup | kp)) undec = 1;
        }
        __syncthreads();
        if (!undec) break;
    }
    if (tid < NW) keepm[tid] = kept[tid];
}

// ---------- K5: final outputs, quality computed inline ----------
__global__ __launch_bounds__(256) void k_out(const float* __restrict__ boxes,
        const float* __restrict__ scores, const float* __restrict__ edgeq,
        const float* __restrict__ mp, const u32* __restrict__ maxab,
        const u64* __restrict__ keepmask, const int* __restrict__ labels,
        float* __restrict__ out) {
    int n = blockIdx.x * 256 + threadIdx.x;
    bool kept = (keepmask[n >> 6] >> (n & 63)) & 1ull;
    float kf = kept ? 1.0f : 0.0f;
    float4 b = ((const float4*)boxes)[n];
    float w = b.z - b.x, h = b.w - b.y;
    float area = w * h;
    float aspect = fminf(w / h, h / w);
    float maxA = __uint_as_float(*maxab);
    float ascore = area / (maxA + 1e-6f);
    ascore = fminf(fmaxf(ascore, 0.f), 1.f);
    float sc = scores[n];
    float det = sc * mp[n] * (aspect * ascore);
    float q = det * 0.4f + 0.3f + edgeq[n] * 0.3f;
    float* o = out + (size_t)n * 6;
    o[0] = b.x * kf; o[1] = b.y * kf; o[2] = b.z * kf; o[3] = b.w * kf;
    o[4] = sc * kf;
    o[5] = q * kf;
    out[6 * NB + n] = kf;
    out[7 * NB + n] = (float)labels[n];
}

extern "C" void kernel_launch(void* const* d_in, const int* in_sizes, int n_in,
                              void* d_out, int out_size, void* d_ws, size_t ws_size,
                              hipStream_t stream) {
    const float* boxes  = (const float*)d_in[0];
    const float* scores = (const float*)d_in[1];
    const float* logits = (const float*)d_in[2];
    const float* feats  = (const float*)d_in[3];
    const int*   labels = (const int*)d_in[4];
    float* out = (float*)d_out;
    char* ws = (char*)d_ws;

    float* edgeq  = (float*)(ws + OFF_EDGEQ);
    float* mp     = (float*)(ws + OFF_MP);
    u64*   keepm  = (u64*)(ws + OFF_KEEP);
    u32*   ecnt   = (u32*)(ws + OFF_ECNT);
    u32*   maxab  = (u32*)(ws + OFF_MAXA);
    u32*   edges  = (u32*)(ws + OFF_EDGES);

    k_edge<<<NB, 256, 0, stream>>>(feats, edgeq, ecnt, maxab);
    k_logit<<<NB / 4, 256, 0, stream>>>(logits, mp);
    dim3 gmat(32, NW);
    k_mat<<<gmat, 256, 0, stream>>>(boxes, scores, ecnt, edges, maxab);
    k_scan4<<<1, 256, 0, stream>>>(ecnt, edges, keepm);
    k_out<<<NB / 256, 256, 0, stream>>>(boxes, scores, edgeq, mp, maxab, keepm, labels, out);
}